// Round 7
// baseline (527.905 us; speedup 1.0000x reference)
//
#include <hip/hip_runtime.h>
#include <hip/hip_bf16.h>

// Problem: out = lecac_linear(relu(lecac_linear(x, W1, b1)), W2, b2)
//   x: [262144, 256] f32, W1: [512,256], b1: [512], W2: [256,512], b2: [256]
// R7: weights kept as PACKED 2-BIT CODES in 32 VGPRs/lane (loaded once),
// unpacked to bf16 fragments on the fly via v_perm byte-LUT (3 VALU / 2 els).
// Kills the recurring L2 weight stream (R2-R5 bottleneck component) AND fits
// the register file (R6 spilled holding bf16 weights: 350 regs > 256 budget).
// Persistent 4-tile blocks, xs double-buffered, 2 raw barriers/tile, x
// prefetched 1 tile ahead in regs, out stores fire-and-forget.

typedef __attribute__((ext_vector_type(8))) short bf16x8;
typedef __attribute__((ext_vector_type(4))) float f32x4;
typedef __attribute__((ext_vector_type(4))) unsigned short us4;

#define D_IN 256
#define D_HID 512
#define D_OUT 256
#define BM 64
#define TILES 4

__device__ __forceinline__ unsigned short f2bf(float f) {
  union { __hip_bfloat16 h; unsigned short u; } c;
  c.h = __float2bfloat16(f);
  return c.u;
}

// Unpack 8 codes (half of a 16-code u32, selected by kkl) -> bf16x8.
// Code c (2 bits): 0->0.0, 1->1.0, 2->-2.0, 3->-1.0 (q & 3 encoding).
// Packing: crumb (byte b, crumb c): j = 2b + (c&1), kkl = c>>1.
__device__ __forceinline__ bf16x8 unpack8(unsigned w, int kkl) {
  unsigned te = (w >> (4 * kkl)) & 0x03030303u;        // els j = 0,2,4,6
  unsigned to = (w >> (4 * kkl + 2)) & 0x03030303u;    // els j = 1,3,5,7
  int4 o;
  unsigned s;
  s = __builtin_amdgcn_perm(to, te, 0x04040000u) + 0x00040004u;
  o.x = (int)__builtin_amdgcn_perm(0x80008000u, 0xBFC03F00u, s);
  s = __builtin_amdgcn_perm(to, te, 0x05050101u) + 0x00040004u;
  o.y = (int)__builtin_amdgcn_perm(0x80008000u, 0xBFC03F00u, s);
  s = __builtin_amdgcn_perm(to, te, 0x06060202u) + 0x00040004u;
  o.z = (int)__builtin_amdgcn_perm(0x80008000u, 0xBFC03F00u, s);
  s = __builtin_amdgcn_perm(to, te, 0x07070303u) + 0x00040004u;
  o.w = (int)__builtin_amdgcn_perm(0x80008000u, 0xBFC03F00u, s);
  return *(bf16x8*)&o;
}

// ---- prep 1: deterministic f64 partial abs-sums (8 chunks per tensor) ------
__global__ void partial_abs_kernel(const float* __restrict__ W1,
                                   const float* __restrict__ W2,
                                   double* __restrict__ part) {
  const int b = blockIdx.x;                 // 0..15
  const float* W = (b < 8) ? W1 : W2;
  const float* p = W + (b & 7) * 16384;     // 131072 / 8
  double s = 0.0;
  for (int i = threadIdx.x; i < 16384; i += 1024) s += (double)fabsf(p[i]);
  __shared__ double red[1024];
  red[threadIdx.x] = s;
  __syncthreads();
  for (int st = 512; st > 0; st >>= 1) {
    if (threadIdx.x < st) red[threadIdx.x] += red[threadIdx.x + st];
    __syncthreads();
  }
  if (threadIdx.x == 0) part[b] = red[0];
}

// ---- prep 2: pack 2-bit codes in the per-lane fragment order ---------------
// pk[0..8192): W1, idx = (wv*64+lane)*16 + mf*4 + kp   (wv<8, mf<4, kp<4)
// pk[8192..16384): W2, idx = (wv*64+lane)*16 + mf*8 + kp (mf<2, kp<8)
__global__ void pack_kernel(const float* __restrict__ W1,
                            const float* __restrict__ W2,
                            const double* __restrict__ part,
                            unsigned* __restrict__ pk,
                            float* __restrict__ fscales) {
  int idx = blockIdx.x * 1024 + threadIdx.x;  // 0..16383
  const double* q = part;
  double sA = 1.47 * ((((q[0]+q[1])+(q[2]+q[3]))+((q[4]+q[5])+(q[6]+q[7]))) / 131072.0) + 1e-8;
  double sB = 1.47 * ((((q[8]+q[9])+(q[10]+q[11]))+((q[12]+q[13])+(q[14]+q[15]))) / 131072.0) + 1e-8;
  if (idx == 0) { fscales[0] = (float)sA; fscales[1] = (float)sB; }
  bool is2 = idx >= 8192;
  int r = idx & 8191;
  int wl = r >> 4;                 // wv*64 + lane
  int wv = wl >> 6, lane = wl & 63;
  int l15 = lane & 15, g = (lane >> 4) & 3;
  int sub = r & 15;
  unsigned word = 0;
  for (int c = 0; c < 4; ++c) {
    for (int b = 0; b < 4; ++b) {
      int j = 2 * b + (c & 1), kkl = c >> 1;
      int code;
      if (!is2) {
        int mf = sub >> 2, kp = sub & 3;
        int row = 64 * wv + 16 * mf + l15;
        int k = 32 * (2 * kp + kkl) + 8 * g + j;
        double v = rint((double)W1[row * 256 + k] / sA);
        code = (int)fmin(fmax(v, -2.0), 1.0) & 3;
      } else {
        int mf = sub >> 3, kp = sub & 7;
        int row = 32 * wv + 16 * mf + l15;
        int k = 32 * (2 * kp + kkl) + 8 * g + j;
        double v = rint((double)W2[row * 512 + k] / sB);
        code = (int)fmin(fmax(v, -2.0), 1.0) & 3;
      }
      word |= (unsigned)code << (8 * b + 2 * c);
    }
  }
  pk[idx] = word;
}

// ---------------- fused MLP kernel ------------------------------------------
// 1024 blocks x 512 threads (8 waves), 1 resident block/CU (128KB LDS),
// TILES=4 tiles of 64 batch rows per block.
// Wave wv: L1 owns hidden [64wv,64wv+64) (mf<4), L2 owns out [32wv,32wv+32)
// (mf<2). Weights live as packed 2-bit codes: 32 u32/lane, loaded once.
__launch_bounds__(512, 2)
__global__ void fused_mlp(const float* __restrict__ x,
                          const float* __restrict__ b1,
                          const float* __restrict__ b2,
                          const unsigned* __restrict__ pk,
                          const float* __restrict__ fscales,
                          float* __restrict__ out) {
  __shared__ unsigned short xs[2][BM * D_IN];   // 2 x 32 KB bf16
  __shared__ unsigned short hs[BM * D_HID];     // 64 KB bf16
  const int t = threadIdx.x;
  const int lane = t & 63;
  const int wv = t >> 6;       // 0..7
  const int l15 = lane & 15;
  const int g = lane >> 4;     // 0..3
  const long tbase = (long)blockIdx.x * TILES;
  const float s1 = fscales[0], s2 = fscales[1];
  const f32x4 zero4 = {0.f, 0.f, 0.f, 0.f};

  // ---- packed weight codes: 32 u32/lane, resident for the whole kernel
  unsigned w1k[16], w2k[16];
  {
    const uint4* p1 = (const uint4*)(pk + (wv * 64 + lane) * 16);
    const uint4* p2 = (const uint4*)(pk + 8192 + (wv * 64 + lane) * 16);
#pragma unroll
    for (int i = 0; i < 4; ++i) {
      uint4 a = p1[i], b = p2[i];
      w1k[4 * i] = a.x; w1k[4 * i + 1] = a.y; w1k[4 * i + 2] = a.z; w1k[4 * i + 3] = a.w;
      w2k[4 * i] = b.x; w2k[4 * i + 1] = b.y; w2k[4 * i + 2] = b.z; w2k[4 * i + 3] = b.w;
    }
  }

  float4 xv[8];  // next-tile x prefetch (32 VGPR)
  auto loadxv = [&](long tile) {
    const float4* p = (const float4*)x + tile * 4096;
#pragma unroll
    for (int j = 0; j < 8; ++j) xv[j] = p[j * 512 + t];
  };
  auto stagex = [&](int buf) {  // xv -> xs[buf], XOR-swizzled (slot ^= row&7)
    unsigned short* xb = xs[buf];
#pragma unroll
    for (int j = 0; j < 8; ++j) {
      int chunk = j * 512 + t;
      int m = chunk >> 6, c4 = chunk & 63;
      int slot = (c4 >> 1) ^ (m & 7);
      us4 o;
      o.x = f2bf(xv[j].x); o.y = f2bf(xv[j].y);
      o.z = f2bf(xv[j].z); o.w = f2bf(xv[j].w);
      *(us4*)&xb[m * 256 + slot * 8 + (c4 & 1) * 4] = o;
    }
  };

  f32x4 acc1[4][4];
  f32x4 acc2[2][4];

  // ---- prologue: stage tile 0, issue loads for tile 1
  loadxv(tbase);
  stagex(0);
  if (TILES > 1) loadxv(tbase + 1);
  asm volatile("s_waitcnt lgkmcnt(0)" ::: "memory");
  __builtin_amdgcn_s_barrier();

  for (int i = 0; i < TILES; ++i) {
    // ========== L1: acc1 = W1q * xs[i&1]^T (K=256, 8 kk steps) ==========
    const unsigned short* xb = xs[i & 1];
#pragma unroll
    for (int a = 0; a < 4; ++a)
#pragma unroll
      for (int b = 0; b < 4; ++b) acc1[a][b] = zero4;
#pragma unroll
    for (int kp = 0; kp < 4; ++kp) {
#pragma unroll
      for (int kkl = 0; kkl < 2; ++kkl) {
        int kk = 2 * kp + kkl;
        bf16x8 bx[4];
#pragma unroll
        for (int nf = 0; nf < 4; ++nf) {
          int m = nf * 16 + l15;
          int slot = (kk * 4 + g) ^ (m & 7);
          bx[nf] = *(const bf16x8*)&xb[m * 256 + slot * 8];
        }
#pragma unroll
        for (int mf = 0; mf < 4; ++mf) {
          bf16x8 fr = unpack8(w1k[mf * 4 + kp], kkl);
#pragma unroll
          for (int nf = 0; nf < 4; ++nf)
            acc1[mf][nf] = __builtin_amdgcn_mfma_f32_16x16x32_bf16(fr, bx[nf], acc1[mf][nf], 0, 0, 0);
        }
      }
    }
    // ========== epi1: hs = relu(s1*acc1 + b1), swizzled ==========
#pragma unroll
    for (int mf = 0; mf < 4; ++mf) {
      int cb = 64 * wv + 16 * mf + 4 * g;
      float4 bb = *(const float4*)&b1[cb];
      int slot_base = cb >> 3;
      int half = (g & 1) * 4;
#pragma unroll
      for (int nf = 0; nf < 4; ++nf) {
        int m = nf * 16 + l15;
        f32x4 a = acc1[mf][nf];
        us4 o;
        o.x = f2bf(fmaxf(s1 * a[0] + bb.x, 0.f));
        o.y = f2bf(fmaxf(s1 * a[1] + bb.y, 0.f));
        o.z = f2bf(fmaxf(s1 * a[2] + bb.z, 0.f));
        o.w = f2bf(fmaxf(s1 * a[3] + bb.w, 0.f));
        int slot = slot_base ^ (m & 7);
        *(us4*)&hs[m * 512 + slot * 8 + half] = o;
      }
    }
    asm volatile("s_waitcnt lgkmcnt(0)" ::: "memory");
    __builtin_amdgcn_s_barrier();   // publish hs(i); xs[i&1] fully consumed

    // stage next x tile (xv consumed -> regs free), then issue loads for i+2
    if (i + 1 < TILES) stagex((i + 1) & 1);
    if (i + 2 < TILES) loadxv(tbase + i + 2);

    // ========== L2: acc2 = W2q * hs^T (K=512, 16 kk steps) ==========
#pragma unroll
    for (int a = 0; a < 2; ++a)
#pragma unroll
      for (int b = 0; b < 4; ++b) acc2[a][b] = zero4;
#pragma unroll
    for (int kp = 0; kp < 8; ++kp) {
#pragma unroll
      for (int kkl = 0; kkl < 2; ++kkl) {
        int kk = 2 * kp + kkl;
        bf16x8 bh[4];
#pragma unroll
        for (int nf = 0; nf < 4; ++nf) {
          int m = nf * 16 + l15;
          int slot = (kk * 4 + g) ^ (m & 7);
          bh[nf] = *(const bf16x8*)&hs[m * 512 + slot * 8];
        }
#pragma unroll
        for (int mf = 0; mf < 2; ++mf) {
          bf16x8 fr = unpack8(w2k[mf * 8 + kp], kkl);
#pragma unroll
          for (int nf = 0; nf < 4; ++nf)
            acc2[mf][nf] = __builtin_amdgcn_mfma_f32_16x16x32_bf16(fr, bh[nf], acc2[mf][nf], 0, 0, 0);
        }
      }
    }
    // ========== epi2: out stores (fire and forget) ==========
    {
      const long row0 = (tbase + i) * BM;
#pragma unroll
      for (int mf = 0; mf < 2; ++mf) {
        int nb = 32 * wv + 16 * mf + 4 * g;
        float4 bb = *(const float4*)&b2[nb];
#pragma unroll
        for (int nf = 0; nf < 4; ++nf) {
          int m = nf * 16 + l15;
          f32x4 a = acc2[mf][nf];
          float4 o;
          o.x = s2 * a[0] + bb.x;
          o.y = s2 * a[1] + bb.y;
          o.z = s2 * a[2] + bb.z;
          o.w = s2 * a[3] + bb.w;
          *(float4*)&out[(row0 + m) * D_OUT + nb] = o;
        }
      }
    }
    asm volatile("s_waitcnt lgkmcnt(0)" ::: "memory");
    __builtin_amdgcn_s_barrier();   // publish xs[i+1]; hs consumed
  }
}

extern "C" void kernel_launch(void* const* d_in, const int* in_sizes, int n_in,
                              void* d_out, int out_size, void* d_ws, size_t ws_size,
                              hipStream_t stream) {
  const float* x  = (const float*)d_in[0];
  const float* W1 = (const float*)d_in[1];
  const float* b1 = (const float*)d_in[2];
  const float* W2 = (const float*)d_in[3];
  const float* b2 = (const float*)d_in[4];
  float* out = (float*)d_out;

  // ws layout: [0,128) f64 partials, [128,136) f32 scales, pk at 1024 (64 KB)
  double* part = (double*)d_ws;
  float* fsc = (float*)((char*)d_ws + 128);
  unsigned* pk = (unsigned*)((char*)d_ws + 1024);

  int Brows = in_sizes[0] / D_IN;     // 262144
  int nblk = Brows / (BM * TILES);    // 1024

  partial_abs_kernel<<<dim3(16), dim3(1024), 0, stream>>>(W1, W2, part);
  pack_kernel<<<dim3(16), dim3(1024), 0, stream>>>(W1, W2, part, pk, fsc);
  fused_mlp<<<dim3(nblk), dim3(512), 0, stream>>>(x, b1, b2, pk, fsc, out);
}